// Round 2
// baseline (3874.192 us; speedup 1.0000x reference)
//
#include <hip/hip_runtime.h>
#include <hip/hip_fp16.h>

#define NPTS 400000
#define MVOX 300000
#define KK 27
#define KD 8
#define CIN 4
#define C0 32
#define NCLS 19
#define EPS 1e-5f

// ---- fp16 pack/unpack helpers (bit_cast style, no local-array aliasing) ----
__device__ __forceinline__ uint32_t pack2(float a, float b) {
    __half2 h = __floats2half2_rn(a, b);
    return __builtin_bit_cast(uint32_t, h);
}
__device__ __forceinline__ float2 unpack2(uint32_t u) {
    return __half22float2(__builtin_bit_cast(__half2, u));
}
__device__ __forceinline__ void unpack8(uint4 u, float* f) {
    float2 a = unpack2(u.x), b = unpack2(u.y), c = unpack2(u.z), d = unpack2(u.w);
    f[0] = a.x; f[1] = a.y; f[2] = b.x; f[3] = b.y;
    f[4] = c.x; f[5] = c.y; f[6] = d.x; f[7] = d.y;
}
__device__ __forceinline__ uint4 pack8(const float* f) {
    return make_uint4(pack2(f[0], f[1]), pack2(f[2], f[3]),
                      pack2(f[4], f[5]), pack2(f[6], f[7]));
}

// ---------------- voxelization ----------------
__global__ void vox_accum(const float* __restrict__ pf, const int* __restrict__ iq,
                          float* __restrict__ counts, float* __restrict__ vox) {
    int i = blockIdx.x * blockDim.x + threadIdx.x;
    if (i >= NPTS) return;
    int q = iq[i];
    float4 f = *reinterpret_cast<const float4*>(pf + (size_t)i * CIN);
    atomicAdd(&counts[q], 1.0f);
    atomicAdd(&vox[q * CIN + 0], f.x);
    atomicAdd(&vox[q * CIN + 1], f.y);
    atomicAdd(&vox[q * CIN + 2], f.z);
    atomicAdd(&vox[q * CIN + 3], f.w);
}

__global__ void vox_div(float* __restrict__ vox, const float* __restrict__ counts) {
    int i = blockIdx.x * blockDim.x + threadIdx.x;
    if (i >= MVOX) return;
    float inv = 1.0f / fmaxf(counts[i], 1.0f);
    float4* vp = reinterpret_cast<float4*>(vox + (size_t)i * CIN);
    float4 v = *vp;
    v.x *= inv; v.y *= inv; v.z *= inv; v.w *= inv;
    *vp = v;
}

// ---------------- conv layer 1 (4 -> 32), fp32 in, fp16 raw out ----------------
__global__ void conv_s1(const float4* __restrict__ x, const int* __restrict__ nbrs,
                        const float* __restrict__ W, uint4* __restrict__ out) {
    int i = blockIdx.x * blockDim.x + threadIdx.x;
    if (i >= MVOX) return;
    float acc[C0];
#pragma unroll
    for (int c = 0; c < C0; c++) acc[c] = 0.f;
    const int* nb = nbrs + (size_t)i * KK;
#pragma unroll
    for (int k = 0; k < KK; k++) {
        int idx = nb[k];
        float m = (idx >= 0) ? 1.f : 0.f;
        float4 xv = x[max(idx, 0)];
        float xs[4] = {m * xv.x, m * xv.y, m * xv.z, m * xv.w};
        const float* wk = W + k * (CIN * C0);
#pragma unroll
        for (int j = 0; j < 4; j++) {
#pragma unroll
            for (int co = 0; co < C0; co++) acc[co] += xs[j] * wk[j * C0 + co];
        }
    }
    uint4* o = out + (size_t)i * 4;
#pragma unroll
    for (int p = 0; p < 4; p++) o[p] = pack8(acc + p * 8);
}

// ------------- conv 32->32: 128 voxels/block, split-K x2, LDS combine -------------
__global__ void conv32_fused(const uint4* __restrict__ x, const int* __restrict__ nbrs,
                             const float* __restrict__ W, uint4* __restrict__ out) {
    __shared__ float lds[128 * 36];
    const int half = threadIdx.x >> 7;   // 0: k in 0..12(+13 masked), 1: k in 13..26
    const int tl = threadIdx.x & 127;
    const int v = blockIdx.x * 128 + tl;
    const bool ok = v < MVOX;
    float acc[C0];
#pragma unroll
    for (int c = 0; c < C0; c++) acc[c] = 0.f;
    if (ok) {
        const int* nb = nbrs + (size_t)v * KK + half * 13;
#pragma unroll
        for (int kk = 0; kk < 14; kk++) {
            const int k = half * 13 + kk;          // wave-uniform, <= 26
            int idx = nb[kk];
            float m = (idx >= 0 && (half == 1 || kk < 13)) ? 1.f : 0.f;
            const uint4* xr = x + (size_t)max(idx, 0) * 4;
            uint4 r0 = xr[0], r1 = xr[1], r2 = xr[2], r3 = xr[3];
            float xs[C0];
            unpack8(r0, xs); unpack8(r1, xs + 8);
            unpack8(r2, xs + 16); unpack8(r3, xs + 24);
            const float* wk = W + k * (C0 * C0);   // wave-uniform -> scalar loads
#pragma unroll
            for (int ci = 0; ci < C0; ci++) {
                float xv = m * xs[ci];
#pragma unroll
                for (int co = 0; co < C0; co++) acc[co] += xv * wk[ci * C0 + co];
            }
        }
    }
    if (half == 1 && ok) {
        float* row = &lds[tl * 36];
#pragma unroll
        for (int c = 0; c < C0; c++) row[c] = acc[c];
    }
    __syncthreads();
    if (half == 0 && ok) {
        const float* row = &lds[tl * 36];
        float f[C0];
#pragma unroll
        for (int c = 0; c < C0; c++) f[c] = acc[c] + row[c];
        uint4* o = out + (size_t)v * 4;
#pragma unroll
        for (int p = 0; p < 4; p++) o[p] = pack8(f + p * 8);
    }
}

// ---------------- batch norm on fp16 tensor ----------------
// sums: [64] = sum[32] | sumsq[32], pre-zeroed
__global__ void bn_stats_h(const uint4* __restrict__ x, float* __restrict__ sums) {
    const int T = MVOX * 4;                 // 8-half chunks
    int t0 = blockIdx.x * blockDim.x + threadIdx.x;
    const int stride = 128 * 256;           // multiple of 4 -> octet fixed per thread
    float s[8], q[8];
#pragma unroll
    for (int j = 0; j < 8; j++) { s[j] = 0.f; q[j] = 0.f; }
    for (int t = t0; t < T; t += stride) {
        float f[8]; unpack8(x[t], f);
#pragma unroll
        for (int j = 0; j < 8; j++) { s[j] += f[j]; q[j] += f[j] * f[j]; }
    }
#pragma unroll
    for (int off = 32; off >= 4; off >>= 1) {
#pragma unroll
        for (int j = 0; j < 8; j++) {
            s[j] += __shfl_down(s[j], off);
            q[j] += __shfl_down(q[j], off);
        }
    }
    int lane = threadIdx.x & 63;
    if (lane < 4) {
        int cb = lane * 8;                  // lane == t0 & 3
#pragma unroll
        for (int j = 0; j < 8; j++) {
            atomicAdd(&sums[cb + j], s[j]);
            atomicAdd(&sums[C0 + cb + j], q[j]);
        }
    }
}

__global__ void bn_finalize(const float* __restrict__ sums, const float* __restrict__ g,
                            const float* __restrict__ b, float* __restrict__ ss) {
    int c = threadIdx.x;
    if (c >= C0) return;
    float mean = sums[c] * (1.0f / (float)MVOX);
    float var = sums[C0 + c] * (1.0f / (float)MVOX) - mean * mean;
    float sc = g[c] * rsqrtf(var + EPS);
    ss[c] = sc;
    ss[C0 + c] = b[c] - mean * sc;
}

__global__ void bn_apply_relu_h(uint4* __restrict__ x, const float* __restrict__ ss) {
    int t = blockIdx.x * blockDim.x + threadIdx.x;
    if (t >= MVOX * 4) return;
    int cb = (t & 3) * 8;
    float f[8]; unpack8(x[t], f);
#pragma unroll
    for (int j = 0; j < 8; j++) f[j] = fmaxf(f[j] * ss[cb + j] + ss[C0 + cb + j], 0.f);
    x[t] = pack8(f);
}

// out = relu(bn(a) + skip)
__global__ void residual_relu_h(const uint4* __restrict__ a, const uint4* __restrict__ skip,
                                const float* __restrict__ ss, uint4* __restrict__ out) {
    int t = blockIdx.x * blockDim.x + threadIdx.x;
    if (t >= MVOX * 4) return;
    int cb = (t & 3) * 8;
    float f[8], h[8];
    unpack8(a[t], f); unpack8(skip[t], h);
#pragma unroll
    for (int j = 0; j < 8; j++) f[j] = fmaxf(f[j] * ss[cb + j] + ss[C0 + cb + j] + h[j], 0.f);
    out[t] = pack8(f);
}

// ---------------- devoxelize + classify ----------------
__global__ void devox_classify(const uint4* __restrict__ H, const int4* __restrict__ idxd,
                               const float4* __restrict__ wdev, const float* __restrict__ Wc,
                               const float* __restrict__ bc, float* __restrict__ out) {
    int i = blockIdx.x * blockDim.x + threadIdx.x;
    if (i >= NPTS) return;
    int4 i0 = idxd[2 * i], i1 = idxd[2 * i + 1];
    float4 w0 = wdev[2 * i], w1 = wdev[2 * i + 1];
    int idxs[8] = {i0.x, i0.y, i0.z, i0.w, i1.x, i1.y, i1.z, i1.w};
    float wsv[8] = {w0.x, w0.y, w0.z, w0.w, w1.x, w1.y, w1.z, w1.w};
    float acc[C0];
#pragma unroll
    for (int c = 0; c < C0; c++) acc[c] = 0.f;
#pragma unroll
    for (int k = 0; k < KD; k++) {
        float m = (idxs[k] >= 0) ? wsv[k] : 0.f;
        const uint4* hr = H + (size_t)max(idxs[k], 0) * 4;
#pragma unroll
        for (int p = 0; p < 4; p++) {
            float f[8]; unpack8(hr[p], f);
#pragma unroll
            for (int j = 0; j < 8; j++) acc[p * 8 + j] += m * f[j];
        }
    }
    float o[NCLS];
#pragma unroll
    for (int c = 0; c < NCLS; c++) o[c] = bc[c];
#pragma unroll
    for (int ci = 0; ci < C0; ci++) {
        float xv = acc[ci];
#pragma unroll
        for (int c = 0; c < NCLS; c++) o[c] += xv * Wc[ci * NCLS + c];
    }
    float* op = out + (size_t)i * NCLS;
#pragma unroll
    for (int c = 0; c < NCLS; c++) op[c] = o[c];
}

extern "C" void kernel_launch(void* const* d_in, const int* in_sizes, int n_in,
                              void* d_out, int out_size, void* d_ws, size_t ws_size,
                              hipStream_t stream) {
    const float* point_fea = (const float*)d_in[0];
    const int*   idx_query = (const int*)d_in[1];
    const int*   nbrs      = (const int*)d_in[2];
    const int*   idx_dev   = (const int*)d_in[3];
    const float* w_dev     = (const float*)d_in[4];
    const float* W_s1      = (const float*)d_in[5];
    const float* W_s2      = (const float*)d_in[6];
    const float* g_s1      = (const float*)d_in[7];
    const float* b_s1      = (const float*)d_in[8];
    const float* g_s2      = (const float*)d_in[9];
    const float* b_s2      = (const float*)d_in[10];
    const float* W_r1      = (const float*)d_in[11];
    const float* W_r2      = (const float*)d_in[12];
    const float* g_r1      = (const float*)d_in[13];
    const float* b_r1      = (const float*)d_in[14];
    const float* g_r2      = (const float*)d_in[15];
    const float* b_r2      = (const float*)d_in[16];
    const float* W_c       = (const float*)d_in[17];
    const float* b_c       = (const float*)d_in[18];
    float* out = (float*)d_out;

    float* ws     = (float*)d_ws;
    float* stats  = ws;                      // 256 floats (4 layers x 64)
    float* ss     = ws + 256;                // 256 floats
    float* counts = ws + 512;                // M
    float* vox    = counts + MVOX;           // 4M fp32
    uint4* A      = (uint4*)(vox + (size_t)4 * MVOX);     // M*32 halfs = M*4 uint4
    uint4* B      = A + (size_t)MVOX * 4;
    uint4* C      = B + (size_t)MVOX * 4;

    // zero atomically-accumulated regions: stats(256)+ss(256)+counts(M)+vox(4M)
    hipMemsetAsync(ws, 0, (size_t)(512 + 5 * MVOX) * sizeof(float), stream);

    dim3 blk(256);
    dim3 gN((NPTS + 255) / 256);
    dim3 gM((MVOX + 255) / 256);
    dim3 gE((MVOX * 4 + 255) / 256);    // 8-half chunks
    dim3 gC((MVOX + 127) / 128);        // conv32_fused: 128 voxels/block

    vox_accum<<<gN, blk, 0, stream>>>(point_fea, idx_query, counts, vox);
    vox_div<<<gM, blk, 0, stream>>>(vox, counts);

    conv_s1<<<gM, blk, 0, stream>>>((const float4*)vox, nbrs, W_s1, A);
    bn_stats_h<<<128, blk, 0, stream>>>(A, stats + 0);
    bn_finalize<<<1, 64, 0, stream>>>(stats + 0, g_s1, b_s1, ss + 0);
    bn_apply_relu_h<<<gE, blk, 0, stream>>>(A, ss + 0);

    conv32_fused<<<gC, blk, 0, stream>>>(A, nbrs, W_s2, B);
    bn_stats_h<<<128, blk, 0, stream>>>(B, stats + 64);
    bn_finalize<<<1, 64, 0, stream>>>(stats + 64, g_s2, b_s2, ss + 64);
    bn_apply_relu_h<<<gE, blk, 0, stream>>>(B, ss + 64);

    conv32_fused<<<gC, blk, 0, stream>>>(B, nbrs, W_r1, C);
    bn_stats_h<<<128, blk, 0, stream>>>(C, stats + 128);
    bn_finalize<<<1, 64, 0, stream>>>(stats + 128, g_r1, b_r1, ss + 128);
    bn_apply_relu_h<<<gE, blk, 0, stream>>>(C, ss + 128);

    conv32_fused<<<gC, blk, 0, stream>>>(C, nbrs, W_r2, A);
    bn_stats_h<<<128, blk, 0, stream>>>(A, stats + 192);
    bn_finalize<<<1, 64, 0, stream>>>(stats + 192, g_r2, b_r2, ss + 192);
    residual_relu_h<<<gE, blk, 0, stream>>>(A, B, ss + 192, C);

    devox_classify<<<gN, blk, 0, stream>>>(C, (const int4*)idx_dev,
                                           (const float4*)w_dev, W_c, b_c, out);
}

// Round 3
// 1096.994 us; speedup vs baseline: 3.5316x; 3.5316x over previous
//
#include <hip/hip_runtime.h>
#include <hip/hip_fp16.h>

#define NPTS 400000
#define MVOX 300000
#define KK 27
#define KD 8
#define CIN 4
#define C0 32
#define NCLS 19
#define EPS 1e-5f
#define NTILE (MVOX / 16)   // 18750 exact

typedef __attribute__((ext_vector_type(8))) _Float16 half8;
typedef __attribute__((ext_vector_type(4))) float f32x4;

// ---- fp16 pack/unpack helpers ----
__device__ __forceinline__ uint32_t pack2(float a, float b) {
    __half2 h = __floats2half2_rn(a, b);
    return __builtin_bit_cast(uint32_t, h);
}
__device__ __forceinline__ float2 unpack2(uint32_t u) {
    return __half22float2(__builtin_bit_cast(__half2, u));
}
__device__ __forceinline__ void unpack8(uint4 u, float* f) {
    float2 a = unpack2(u.x), b = unpack2(u.y), c = unpack2(u.z), d = unpack2(u.w);
    f[0] = a.x; f[1] = a.y; f[2] = b.x; f[3] = b.y;
    f[4] = c.x; f[5] = c.y; f[6] = d.x; f[7] = d.y;
}
__device__ __forceinline__ uint4 pack8(const float* f) {
    return make_uint4(pack2(f[0], f[1]), pack2(f[2], f[3]),
                      pack2(f[4], f[5]), pack2(f[6], f[7]));
}

// ---------------- voxelization ----------------
__global__ void vox_accum(const float* __restrict__ pf, const int* __restrict__ iq,
                          float* __restrict__ counts, float* __restrict__ vox) {
    int i = blockIdx.x * blockDim.x + threadIdx.x;
    if (i >= NPTS) return;
    int q = iq[i];
    float4 f = *reinterpret_cast<const float4*>(pf + (size_t)i * CIN);
    atomicAdd(&counts[q], 1.0f);
    atomicAdd(&vox[q * CIN + 0], f.x);
    atomicAdd(&vox[q * CIN + 1], f.y);
    atomicAdd(&vox[q * CIN + 2], f.z);
    atomicAdd(&vox[q * CIN + 3], f.w);
}

// vox fp32 -> fp16 rows (8B)
__global__ void vox_div_h(const float4* __restrict__ vox, const float* __restrict__ counts,
                          uint2* __restrict__ voxh) {
    int i = blockIdx.x * blockDim.x + threadIdx.x;
    if (i >= MVOX) return;
    float inv = 1.0f / fmaxf(counts[i], 1.0f);
    float4 v = vox[i];
    voxh[i] = make_uint2(pack2(v.x * inv, v.y * inv), pack2(v.z * inv, v.w * inv));
}

// ------------- W prep: [k][ci][co] fp32 -> per-lane B-fragment fp16 -------------
// Wf[layer*3456 + k*128 + h*64 + lane] = 8 halves: W[k][(lane>>4)*8 + j][h*16 + (lane&15)]
__global__ void wprep(const float* __restrict__ W0, const float* __restrict__ W1,
                      const float* __restrict__ W2, uint4* __restrict__ Wf) {
    int t = blockIdx.x * blockDim.x + threadIdx.x;
    if (t >= 3 * KK * 128) return;
    int layer = t / (KK * 128);
    int rem = t % (KK * 128);
    int k = rem / 128;
    int h = (rem >> 6) & 1;
    int lane = rem & 63;
    const float* W = (layer == 0) ? W0 : (layer == 1) ? W1 : W2;
    const float* wk = W + k * (C0 * C0);
    int co = h * 16 + (lane & 15);
    int ci0 = (lane >> 4) * 8;
    float f[8];
#pragma unroll
    for (int j = 0; j < 8; j++) f[j] = wk[(ci0 + j) * C0 + co];
    Wf[t] = pack8(f);
}

// ---------------- conv layer 1 (4 -> 32), fp16 in, fp16 raw out ----------------
__global__ void conv_s1_h(const uint2* __restrict__ x, const int* __restrict__ nbrs,
                          const float* __restrict__ W, uint4* __restrict__ out) {
    int i = blockIdx.x * blockDim.x + threadIdx.x;
    if (i >= MVOX) return;
    float acc[C0];
#pragma unroll
    for (int c = 0; c < C0; c++) acc[c] = 0.f;
    const int* nb = nbrs + (size_t)i * KK;
#pragma unroll
    for (int k = 0; k < KK; k++) {
        int idx = nb[k];
        float m = (idx >= 0) ? 1.f : 0.f;
        uint2 r = x[idx < 0 ? 0 : idx];
        float2 ab = unpack2(r.x), cd = unpack2(r.y);
        float xs[4] = {m * ab.x, m * ab.y, m * cd.x, m * cd.y};
        const float* wk = W + k * (CIN * C0);   // k uniform -> scalar loads
#pragma unroll
        for (int j = 0; j < 4; j++) {
#pragma unroll
            for (int co = 0; co < C0; co++) acc[co] += xs[j] * wk[j * C0 + co];
        }
    }
    uint4* o = out + (size_t)i * 4;
#pragma unroll
    for (int p = 0; p < 4; p++) o[p] = pack8(acc + p * 8);
}

// ------------- conv 32->32 via MFMA: one wave = 16 voxels, K=ci=32 -------------
__global__ __launch_bounds__(256) void conv32_mfma(const uint4* __restrict__ x,
                                                   const int* __restrict__ nbrs,
                                                   const uint4* __restrict__ Wf,
                                                   __half* __restrict__ out) {
    const int lane = threadIdx.x & 63;
    const int wid = threadIdx.x >> 6;
    const int tile = blockIdx.x * 4 + wid;
    if (tile >= NTILE) return;
    const int row = lane & 15;          // voxel within tile (A row)
    const int chunk = lane >> 4;        // which 8-ci chunk (A k-group)
    const int vr = tile * 16 + row;
    const int* nb = nbrs + (size_t)vr * KK;
    f32x4 acc0 = {0.f, 0.f, 0.f, 0.f}, acc1 = {0.f, 0.f, 0.f, 0.f};
#pragma unroll
    for (int k = 0; k < KK; k++) {
        int idx = nb[k];
        uint4 ar = x[(size_t)(idx < 0 ? 0 : idx) * 4 + chunk];
        if (idx < 0) ar = make_uint4(0, 0, 0, 0);
        half8 a = __builtin_bit_cast(half8, ar);
        half8 b0 = __builtin_bit_cast(half8, Wf[k * 128 + lane]);
        half8 b1 = __builtin_bit_cast(half8, Wf[k * 128 + 64 + lane]);
        acc0 = __builtin_amdgcn_mfma_f32_16x16x32_f16(a, b0, acc0, 0, 0, 0);
        acc1 = __builtin_amdgcn_mfma_f32_16x16x32_f16(a, b1, acc1, 0, 0, 0);
    }
    // D layout: col = lane&15, row = chunk*4 + reg
    __half* obase = out + (size_t)tile * 16 * C0;
    const int col = lane & 15;
#pragma unroll
    for (int r = 0; r < 4; r++) {
        int orow = chunk * 4 + r;
        obase[orow * C0 + col] = __float2half(acc0[r]);
        obase[orow * C0 + 16 + col] = __float2half(acc1[r]);
    }
}

// ---------------- batch norm on fp16 tensor ----------------
__global__ void bn_stats_h(const uint4* __restrict__ x, float* __restrict__ sums) {
    const int T = MVOX * 4;
    int t0 = blockIdx.x * blockDim.x + threadIdx.x;
    const int stride = 128 * 256;
    float s[8], q[8];
#pragma unroll
    for (int j = 0; j < 8; j++) { s[j] = 0.f; q[j] = 0.f; }
    for (int t = t0; t < T; t += stride) {
        float f[8]; unpack8(x[t], f);
#pragma unroll
        for (int j = 0; j < 8; j++) { s[j] += f[j]; q[j] += f[j] * f[j]; }
    }
#pragma unroll
    for (int off = 32; off >= 4; off >>= 1) {
#pragma unroll
        for (int j = 0; j < 8; j++) {
            s[j] += __shfl_down(s[j], off);
            q[j] += __shfl_down(q[j], off);
        }
    }
    int lane = threadIdx.x & 63;
    if (lane < 4) {
        int cb = lane * 8;
#pragma unroll
        for (int j = 0; j < 8; j++) {
            atomicAdd(&sums[cb + j], s[j]);
            atomicAdd(&sums[C0 + cb + j], q[j]);
        }
    }
}

__global__ void bn_finalize(const float* __restrict__ sums, const float* __restrict__ g,
                            const float* __restrict__ b, float* __restrict__ ss) {
    int c = threadIdx.x;
    if (c >= C0) return;
    float mean = sums[c] * (1.0f / (float)MVOX);
    float var = sums[C0 + c] * (1.0f / (float)MVOX) - mean * mean;
    float sc = g[c] * rsqrtf(var + EPS);
    ss[c] = sc;
    ss[C0 + c] = b[c] - mean * sc;
}

__global__ void bn_apply_relu_h(uint4* __restrict__ x, const float* __restrict__ ss) {
    int t = blockIdx.x * blockDim.x + threadIdx.x;
    if (t >= MVOX * 4) return;
    int cb = (t & 3) * 8;
    float f[8]; unpack8(x[t], f);
#pragma unroll
    for (int j = 0; j < 8; j++) f[j] = fmaxf(f[j] * ss[cb + j] + ss[C0 + cb + j], 0.f);
    x[t] = pack8(f);
}

// x = relu(bn(x) + skip), in place
__global__ void residual_relu_h(uint4* __restrict__ x, const uint4* __restrict__ skip,
                                const float* __restrict__ ss) {
    int t = blockIdx.x * blockDim.x + threadIdx.x;
    if (t >= MVOX * 4) return;
    int cb = (t & 3) * 8;
    float f[8], h[8];
    unpack8(x[t], f); unpack8(skip[t], h);
#pragma unroll
    for (int j = 0; j < 8; j++) f[j] = fmaxf(f[j] * ss[cb + j] + ss[C0 + cb + j] + h[j], 0.f);
    x[t] = pack8(f);
}

// ---------------- devoxelize + classify ----------------
__global__ void devox_classify(const uint4* __restrict__ H, const int4* __restrict__ idxd,
                               const float4* __restrict__ wdev, const float* __restrict__ Wc,
                               const float* __restrict__ bc, float* __restrict__ out) {
    int i = blockIdx.x * blockDim.x + threadIdx.x;
    if (i >= NPTS) return;
    int4 i0 = idxd[2 * i], i1 = idxd[2 * i + 1];
    float4 w0 = wdev[2 * i], w1 = wdev[2 * i + 1];
    int idxs[8] = {i0.x, i0.y, i0.z, i0.w, i1.x, i1.y, i1.z, i1.w};
    float wsv[8] = {w0.x, w0.y, w0.z, w0.w, w1.x, w1.y, w1.z, w1.w};
    float acc[C0];
#pragma unroll
    for (int c = 0; c < C0; c++) acc[c] = 0.f;
#pragma unroll
    for (int k = 0; k < KD; k++) {
        float m = (idxs[k] >= 0) ? wsv[k] : 0.f;
        const uint4* hr = H + (size_t)(idxs[k] < 0 ? 0 : idxs[k]) * 4;
#pragma unroll
        for (int p = 0; p < 4; p++) {
            float f[8]; unpack8(hr[p], f);
#pragma unroll
            for (int j = 0; j < 8; j++) acc[p * 8 + j] += m * f[j];
        }
    }
    float o[NCLS];
#pragma unroll
    for (int c = 0; c < NCLS; c++) o[c] = bc[c];
#pragma unroll
    for (int ci = 0; ci < C0; ci++) {
        float xv = acc[ci];
#pragma unroll
        for (int c = 0; c < NCLS; c++) o[c] += xv * Wc[ci * NCLS + c];
    }
    float* op = out + (size_t)i * NCLS;
#pragma unroll
    for (int c = 0; c < NCLS; c++) op[c] = o[c];
}

extern "C" void kernel_launch(void* const* d_in, const int* in_sizes, int n_in,
                              void* d_out, int out_size, void* d_ws, size_t ws_size,
                              hipStream_t stream) {
    const float* point_fea = (const float*)d_in[0];
    const int*   idx_query = (const int*)d_in[1];
    const int*   nbrs      = (const int*)d_in[2];
    const int*   idx_dev   = (const int*)d_in[3];
    const float* w_dev     = (const float*)d_in[4];
    const float* W_s1      = (const float*)d_in[5];
    const float* W_s2      = (const float*)d_in[6];
    const float* g_s1      = (const float*)d_in[7];
    const float* b_s1      = (const float*)d_in[8];
    const float* g_s2      = (const float*)d_in[9];
    const float* b_s2      = (const float*)d_in[10];
    const float* W_r1      = (const float*)d_in[11];
    const float* W_r2      = (const float*)d_in[12];
    const float* g_r1      = (const float*)d_in[13];
    const float* b_r1      = (const float*)d_in[14];
    const float* g_r2      = (const float*)d_in[15];
    const float* b_r2      = (const float*)d_in[16];
    const float* W_c       = (const float*)d_in[17];
    const float* b_c       = (const float*)d_in[18];
    float* out = (float*)d_out;

    float* ws = (float*)d_ws;
    const size_t M = MVOX;
    float* stats  = ws;                        // 256
    float* ss     = ws + 256;                  // 256
    float* counts = ws + 512;                  // M
    float* vox32  = counts + M;                // 4M fp32  [memset through here]
    uint2* voxh   = (uint2*)(vox32 + 4 * M);   // M * 8B
    uint4* Wf     = (uint4*)((float*)voxh + 2 * M);  // 3*27*128 uint4 = 165888B
    float* bufs   = (float*)Wf + 3 * KK * 128 * 4;
    uint4* A = (uint4*)bufs;                   // M*32 halfs = 4.8M floats
    uint4* B = A + M * 4;
    uint4* C = B + M * 4;
    uint4* D = C + M * 4;

    hipMemsetAsync(ws, 0, (size_t)(512 + 5 * M) * sizeof(float), stream);

    dim3 blk(256);
    dim3 gN((NPTS + 255) / 256);
    dim3 gM((MVOX + 255) / 256);
    dim3 gE((MVOX * 4 + 255) / 256);
    dim3 gT((NTILE + 3) / 4);          // conv32_mfma: 4 waves/block, 1 tile/wave
    dim3 gW((3 * KK * 128 + 255) / 256);

    vox_accum<<<gN, blk, 0, stream>>>(point_fea, idx_query, counts, vox32);
    vox_div_h<<<gM, blk, 0, stream>>>((const float4*)vox32, counts, voxh);
    wprep<<<gW, blk, 0, stream>>>(W_s2, W_r1, W_r2, Wf);

    conv_s1_h<<<gM, blk, 0, stream>>>(voxh, nbrs, W_s1, A);
    bn_stats_h<<<128, blk, 0, stream>>>(A, stats + 0);
    bn_finalize<<<1, 64, 0, stream>>>(stats + 0, g_s1, b_s1, ss + 0);
    bn_apply_relu_h<<<gE, blk, 0, stream>>>(A, ss + 0);

    conv32_mfma<<<gT, blk, 0, stream>>>(A, nbrs, Wf + 0 * KK * 128, (__half*)B);
    bn_stats_h<<<128, blk, 0, stream>>>(B, stats + 64);
    bn_finalize<<<1, 64, 0, stream>>>(stats + 64, g_s2, b_s2, ss + 64);
    bn_apply_relu_h<<<gE, blk, 0, stream>>>(B, ss + 64);

    conv32_mfma<<<gT, blk, 0, stream>>>(B, nbrs, Wf + 1 * KK * 128, (__half*)C);
    bn_stats_h<<<128, blk, 0, stream>>>(C, stats + 128);
    bn_finalize<<<1, 64, 0, stream>>>(stats + 128, g_r1, b_r1, ss + 128);
    bn_apply_relu_h<<<gE, blk, 0, stream>>>(C, ss + 128);

    conv32_mfma<<<gT, blk, 0, stream>>>(C, nbrs, Wf + 2 * KK * 128, (__half*)D);
    bn_stats_h<<<128, blk, 0, stream>>>(D, stats + 192);
    bn_finalize<<<1, 64, 0, stream>>>(stats + 192, g_r2, b_r2, ss + 192);
    residual_relu_h<<<gE, blk, 0, stream>>>(D, B, ss + 192);

    devox_classify<<<gN, blk, 0, stream>>>(D, (const int4*)idx_dev,
                                           (const float4*)w_dev, W_c, b_c, out);
}